// Round 12
// baseline (288.037 us; speedup 1.0000x reference)
//
#include <hip/hip_runtime.h>
#include <hip/hip_bf16.h>
#include <math.h>

#define N_NODES 50000
#define F_IN 128
#define HID 64
#define NCLS 40
#define K_STACKS 2
#define SCAN_TILE 1024
#define NBLK_CNT 256  // radix blocks; 256 buckets of 256 node-ids (N=50000 -> 196 used)

typedef __attribute__((ext_vector_type(8))) short short8;
typedef __attribute__((ext_vector_type(4))) float floatx4;
typedef __attribute__((ext_vector_type(2))) float floatx2;

__device__ __forceinline__ unsigned int f32_to_bf16_bits(float f) {
    unsigned int u = __float_as_uint(f);
    return (u + 0x7fffu + ((u >> 16) & 1u)) >> 16;  // RNE
}
__device__ __forceinline__ unsigned int pack_bf16x2(float a, float b) {
    return f32_to_bf16_bits(a) | (f32_to_bf16_bits(b) << 16);
}
__device__ __forceinline__ unsigned char f32_to_fp8(float v) {
    int pk = __builtin_amdgcn_cvt_pk_fp8_f32(v, v, 0, false);  // OCP e4m3 on gfx950
    return (unsigned char)(pk & 0xff);
}

// ---------------- CSR build via radix bucketing (dst>>8) ----------------
// NOTE: packing src into 16 bits requires N <= 65536 (here N=50000).

// counts histogram + per-scan-tile sums (tile i covers buckets 4i..4i+3)
__global__ __launch_bounds__(256) void count_kernel(const int* __restrict__ dst,
                                                    int* __restrict__ counts,
                                                    int* __restrict__ tileSums, int E) {
    __shared__ int hist[256];
    __shared__ int ts[64];
    int blk = blockIdx.x, t = threadIdx.x;
    hist[t] = 0;
    if (t < 64) ts[t] = 0;
    __syncthreads();
    int chunk = (E + NBLK_CNT - 1) / NBLK_CNT;
    int s = blk * chunk, e = min(E, s + chunk);
    for (int i = s + t; i < e; i += 256) atomicAdd(&hist[dst[i] >> 8], 1);
    __syncthreads();
    counts[t * NBLK_CNT + blk] = hist[t];  // bucket-major
    atomicAdd(&ts[t >> 2], hist[t]);
    __syncthreads();
    if (t < 64) atomicAdd(&tileSums[t], ts[t]);
}

// exclusive scan of counts; tile offsets computed in-block from tileSums
__global__ __launch_bounds__(256) void scan_phase3_excl(const int* __restrict__ in,
                                                        const int* __restrict__ tileSums,
                                                        int* __restrict__ out, int n) {
    __shared__ int lds[256];
    __shared__ int tsum[64];
    int b = blockIdx.x, t = threadIdx.x;
    if (t < 64) tsum[t] = tileSums[t];
    int base = b * SCAN_TILE + t * 4;
    int e[4];
    int s = 0;
#pragma unroll
    for (int i = 0; i < 4; ++i) {
        e[i] = (base + i < n) ? in[base + i] : 0;
        s += e[i];
    }
    lds[t] = s;
    __syncthreads();
    int v = s;
    for (int off = 1; off < 256; off <<= 1) {
        int add = (t >= off) ? lds[t - off] : 0;
        __syncthreads();
        v += add;
        lds[t] = v;
        __syncthreads();
    }
    int toff = 0;
    for (int i = 0; i < b; ++i) toff += tsum[i];
    int run = (t == 0 ? 0 : lds[t - 1]) + toff;
#pragma unroll
    for (int i = 0; i < 4; ++i) {
        if (base + i < n) {
            out[base + i] = run;
            run += e[i];
        }
    }
}

// dense bucketed writes: each block owns pre-reserved runs per bucket
__global__ __launch_bounds__(256) void bucket_scatter_kernel(const int* __restrict__ src,
                                                             const int* __restrict__ dst,
                                                             const int* __restrict__ scanned,
                                                             unsigned int* __restrict__ pairs,
                                                             int E) {
    __shared__ int cur[256];
    int blk = blockIdx.x, t = threadIdx.x;
    cur[t] = scanned[t * NBLK_CNT + blk];
    __syncthreads();
    int chunk = (E + NBLK_CNT - 1) / NBLK_CNT;
    int s0 = blk * chunk, e0 = min(E, s0 + chunk);
    for (int i = s0 + t; i < e0; i += 256) {
        int d = dst[i];
        int pos = atomicAdd(&cur[d >> 8], 1);
        pairs[pos] = (unsigned int)src[i] | ((unsigned int)(d & 255) << 16);
    }
}

// one block per bucket: local deg hist -> scan -> row_ptr/dinv/col (all L2-local)
__global__ __launch_bounds__(256) void csr_build_kernel(const unsigned int* __restrict__ pairs,
                                                        const int* __restrict__ scanned,
                                                        int* __restrict__ row_ptr,
                                                        float* __restrict__ dinv,
                                                        int* __restrict__ col, int N, int E) {
    __shared__ int degl[256], lds[256], curl[256], sb[2];
    int b = blockIdx.x, t = threadIdx.x;
    if (t == 0) {
        sb[0] = scanned[b * NBLK_CNT];
        sb[1] = (b + 1 < 256) ? scanned[(b + 1) * NBLK_CNT] : E;
    }
    degl[t] = 0;
    __syncthreads();
    int bstart = sb[0], bend = sb[1];
    for (int e = bstart + t; e < bend; e += 256) {
        atomicAdd(&degl[(pairs[e] >> 16) & 255], 1);
    }
    __syncthreads();
    int d = degl[t];
    lds[t] = d;
    __syncthreads();
    int v = d;
    for (int off = 1; off < 256; off <<= 1) {
        int add = (t >= off) ? lds[t - off] : 0;
        __syncthreads();
        v += add;
        lds[t] = v;
        __syncthreads();
    }
    int excl = v - d;
    int node = b * 256 + t;
    if (node <= N) row_ptr[node] = bstart + excl;
    if (node < N) dinv[node] = (d > 0) ? (1.0f / sqrtf((float)d)) : 0.0f;
    curl[t] = excl;
    __syncthreads();
    for (int e = bstart + t; e < bend; e += 256) {
        unsigned int p = pairs[e];
        int ln = (p >> 16) & 255;
        int pos = atomicAdd(&curl[ln], 1);
        col[bstart + pos] = (int)(p & 0xffffu);
    }
}

// ---------------- fused weight pre-transpose: [k][C][F] fp32 -> [k][F][CP] bf16 ----------
__device__ __forceinline__ void wt_one(const float* __restrict__ in,
                                       unsigned short* __restrict__ out, int li, int C, int F,
                                       int CP) {
    int k = li / (F * CP);
    int r = li - k * F * CP;
    int f = r / CP;
    int c = r - f * CP;
    out[li] = (c < C) ? (unsigned short)f32_to_bf16_bits(in[((size_t)k * C + c) * F + f]) : 0;
}

__global__ void wt_all_kernel(const float* v1, const float* w1i, const float* w1,
                              const float* v2, const float* w2i, const float* w2,
                              unsigned short* v1t, unsigned short* w1it, unsigned short* w1t,
                              unsigned short* v2t, unsigned short* w2it, unsigned short* w2t) {
    int i = blockIdx.x * blockDim.x + threadIdx.x;
    if (i < 16384) wt_one(v1, v1t, i, 128, 64, 128);
    else if (i < 32768) wt_one(w1i, w1it, i - 16384, 128, 64, 128);
    else if (i < 40960) wt_one(w1, w1t, i - 32768, 64, 64, 64);
    else if (i < 46080) wt_one(v2, v2t, i - 40960, 64, 40, 64);
    else if (i < 51200) wt_one(w2i, w2it, i - 46080, 64, 40, 64);
    else if (i < 56320) wt_one(w2, w2t, i - 51200, 40, 40, 64);
}

// ---------------- staging helpers ----------------
template <int CINP>
__device__ __forceinline__ void stage_A(const void* A, unsigned short* At, size_t abase,
                                        int n0, int t, int N, int CREAL, int a_bf16) {
    constexpr int CP8 = CINP / 8;
    constexpr int MS = CP8 - 1;
    constexpr int SH = (CP8 == 16) ? 4 : 3;
    for (int i = t; i < 64 * CP8; i += 256) {
        int n = i >> SH;
        int c = i & MS;
        uint4 w = make_uint4(0u, 0u, 0u, 0u);
        int gn = n0 + n;
        if (gn < N && c * 8 < CREAL) {
            if (a_bf16) {
                w = *(const uint4*)((const unsigned short*)A + abase + (size_t)gn * CREAL + c * 8);
            } else {
                const float* srcp = (const float*)A + abase + (size_t)gn * CREAL + c * 8;
                float4 f0 = *(const float4*)(srcp);
                float4 f1 = *(const float4*)(srcp + 4);
                w.x = pack_bf16x2(f0.x, f0.y);
                w.y = pack_bf16x2(f0.z, f0.w);
                w.z = pack_bf16x2(f1.x, f1.y);
                w.w = pack_bf16x2(f1.z, f1.w);
            }
        }
        *(uint4*)(At + n * CINP + ((c ^ (n & MS)) << 3)) = w;
    }
}

template <int CINP>
__device__ __forceinline__ void stage_B(const unsigned short* Bk, unsigned short* Bs, int t,
                                        int COUT) {
    constexpr int CP8 = CINP / 8;
    constexpr int MS = CP8 - 1;
    constexpr int SH = (CP8 == 16) ? 4 : 3;
    for (int i = t; i < COUT * CP8; i += 256) {
        int f = i >> SH;
        int c = i & MS;
        uint4 w = *(const uint4*)(Bk + f * CINP + c * 8);
        *(uint4*)(Bs + f * CINP + ((c ^ (f & MS)) << 3)) = w;
    }
}

// ---------------- MFMA GEMM (single output, per-k grid) ----------------
// out_inter=1 + out_fp8=1: fp8 gather-table [node][k][COUT]; else f32 std.
template <int CINP>
__global__ __launch_bounds__(256) void gemm_mfma(
    const void* __restrict__ A, const unsigned short* __restrict__ Bt,
    void* __restrict__ out, const float* __restrict__ scale, int N, int COUT, int CREAL,
    int a_per_k, int a_bf16, int out_fp8, int do_scale, int out_inter) {
    constexpr int MS = CINP / 8 - 1;
    __shared__ __align__(16) unsigned short At[64 * CINP];
    __shared__ __align__(16) unsigned short Bs[64 * CINP];

    const int k = blockIdx.y;
    const int n0 = blockIdx.x * 64;
    const int t = threadIdx.x;
    stage_A<CINP>(A, At, a_per_k ? (size_t)k * N * CREAL : (size_t)0, n0, t, N, CREAL, a_bf16);
    stage_B<CINP>(Bt + (size_t)k * COUT * CINP, Bs, t, COUT);
    __syncthreads();

    const int lane = t & 63;
    const int wv = t >> 6;
    const int quad = lane >> 4;
    const int li = lane & 15;
    const int m0 = wv * 16;

    floatx4 acc[4] = {{0.f, 0.f, 0.f, 0.f}, {0.f, 0.f, 0.f, 0.f},
                      {0.f, 0.f, 0.f, 0.f}, {0.f, 0.f, 0.f, 0.f}};
    const int am = (m0 + li) & MS;
#pragma unroll
    for (int kc = 0; kc < CINP / 32; ++kc) {
        int cc = kc * 4 + quad;
        short8 a = *(const short8*)(At + (m0 + li) * CINP + ((cc ^ am) << 3));
#pragma unroll
        for (int nt = 0; nt < 4; ++nt) {
            if (nt * 16 < COUT) {
                int f = nt * 16 + li;
                short8 b = *(const short8*)(Bs + f * CINP + ((cc ^ (f & MS)) << 3));
                acc[nt] = __builtin_amdgcn_mfma_f32_16x16x32_bf16(a, b, acc[nt], 0, 0, 0);
            }
        }
    }

    float sc[4] = {1.f, 1.f, 1.f, 1.f};
    if (do_scale) {
#pragma unroll
        for (int r = 0; r < 4; ++r) {
            int node = n0 + m0 + quad * 4 + r;
            sc[r] = (node < N) ? scale[node] : 1.f;
        }
    }
#pragma unroll
    for (int nt = 0; nt < 4; ++nt) {
        if (nt * 16 >= COUT) continue;
        int f = nt * 16 + li;
        if (f >= COUT) continue;
#pragma unroll
        for (int r = 0; r < 4; ++r) {
            int node = n0 + m0 + quad * 4 + r;
            if (node < N) {
                float val = acc[nt][r] * sc[r];
                if (out_inter) {
                    size_t o = (size_t)node * 2 * COUT + (size_t)k * COUT + f;
                    if (out_fp8)
                        ((unsigned char*)out)[o] = f32_to_fp8(val);
                    else
                        ((unsigned short*)out)[o] = (unsigned short)f32_to_bf16_bits(val);
                } else {
                    size_t o = ((size_t)k * N + node) * COUT + f;
                    ((float*)out)[o] = val;
                }
            }
        }
    }
}

// ---------------- MFMA GEMM fused pair, k-loop inside (A staged once) ----------------
// shared A -> root (bf16 std [k][N][COUT]) + table (fp8 inter [node][k][COUT], dinv-scaled)
template <int CINP>
__global__ __launch_bounds__(256) void gemm2_mfma(
    const void* __restrict__ A, const unsigned short* __restrict__ Bt1,
    const unsigned short* __restrict__ Bt2, unsigned short* __restrict__ out1,
    unsigned char* __restrict__ out2, const float* __restrict__ scale, int N, int COUT,
    int CREAL, int a_bf16) {
    constexpr int MS = CINP / 8 - 1;
    __shared__ __align__(16) unsigned short At[64 * CINP];
    __shared__ __align__(16) unsigned short Bs1[64 * CINP];
    __shared__ __align__(16) unsigned short Bs2[64 * CINP];

    const int n0 = blockIdx.x * 64;
    const int t = threadIdx.x;
    stage_A<CINP>(A, At, (size_t)0, n0, t, N, CREAL, a_bf16);

    const int lane = t & 63;
    const int wv = t >> 6;
    const int quad = lane >> 4;
    const int li = lane & 15;
    const int m0 = wv * 16;
    const int am = (m0 + li) & MS;

    float sc[4];
#pragma unroll
    for (int r = 0; r < 4; ++r) {
        int node = n0 + m0 + quad * 4 + r;
        sc[r] = (node < N) ? scale[node] : 1.f;
    }

    for (int k = 0; k < 2; ++k) {
        if (k) __syncthreads();  // all waves done reading previous Bs
        stage_B<CINP>(Bt1 + (size_t)k * COUT * CINP, Bs1, t, COUT);
        stage_B<CINP>(Bt2 + (size_t)k * COUT * CINP, Bs2, t, COUT);
        __syncthreads();

        floatx4 acc1[4] = {{0.f, 0.f, 0.f, 0.f}, {0.f, 0.f, 0.f, 0.f},
                           {0.f, 0.f, 0.f, 0.f}, {0.f, 0.f, 0.f, 0.f}};
        floatx4 acc2[4] = {{0.f, 0.f, 0.f, 0.f}, {0.f, 0.f, 0.f, 0.f},
                           {0.f, 0.f, 0.f, 0.f}, {0.f, 0.f, 0.f, 0.f}};
#pragma unroll
        for (int kc = 0; kc < CINP / 32; ++kc) {
            int cc = kc * 4 + quad;
            short8 a = *(const short8*)(At + (m0 + li) * CINP + ((cc ^ am) << 3));
#pragma unroll
            for (int nt = 0; nt < 4; ++nt) {
                if (nt * 16 < COUT) {
                    int f = nt * 16 + li;
                    int bo = f * CINP + ((cc ^ (f & MS)) << 3);
                    short8 b1 = *(const short8*)(Bs1 + bo);
                    short8 b2 = *(const short8*)(Bs2 + bo);
                    acc1[nt] = __builtin_amdgcn_mfma_f32_16x16x32_bf16(a, b1, acc1[nt], 0, 0, 0);
                    acc2[nt] = __builtin_amdgcn_mfma_f32_16x16x32_bf16(a, b2, acc2[nt], 0, 0, 0);
                }
            }
        }
#pragma unroll
        for (int nt = 0; nt < 4; ++nt) {
            if (nt * 16 >= COUT) continue;
            int f = nt * 16 + li;
            if (f >= COUT) continue;
#pragma unroll
            for (int r = 0; r < 4; ++r) {
                int node = n0 + m0 + quad * 4 + r;
                if (node < N) {
                    out1[((size_t)k * N + node) * COUT + f] =
                        (unsigned short)f32_to_bf16_bits(acc1[nt][r]);
                    out2[(size_t)node * 2 * COUT + (size_t)k * COUT + f] =
                        f32_to_fp8(acc2[nt][r] * sc[r]);
                }
            }
        }
    }
}

// ---------------- Sparse aggregation v8: fp8 table, 2 nodes/wave, fused mean+lsm --------
// h8 interleaved [node][k][F] fp8 (pre-scaled by dinv[src]). Each 32-lane half owns a node.
// mode 0: bf16 std [k][N][F] out.  mode 1: fp32 mean-over-k out [N][F].
// mode 2: mean-over-k -> in-wave log_softmax over F=NCLS feats -> fp32 out [N][F].
template <int F>
__global__ __launch_bounds__(256) void agg_kernel(
    const unsigned char* __restrict__ h8, const int* __restrict__ row_ptr,
    const int* __restrict__ col, const float* __restrict__ dinv,
    const unsigned short* __restrict__ rootb, const float* __restrict__ bias,
    void* __restrict__ out, int N, int do_relu, int mode) {
    constexpr int FH = F / 8;
    constexpr int ROWB = 2 * F;  // interleaved row bytes (fp8)
    int wid = (blockIdx.x * blockDim.x + threadIdx.x) >> 6;
    int lane = threadIdx.x & 63;
    int half = lane >> 5;
    int l32 = lane & 31;
    int node = wid * 2 + half;
    bool valid = node < N;
    int e0 = 0, deg = 0;
    float dv = 0.f;
    if (valid) {
        e0 = row_ptr[node];
        deg = row_ptr[node + 1] - e0;
        dv = dinv[node];
    }
    const int sub = l32 >> 4;
    const int fq = l32 & 15;
    const int kk = fq >> 3;
    const int fqq = fq & 7;
    const int fqc = (fqq < FH) ? fqq : (FH - 1);
    const int foff = kk * F + fqc * 8;

    float acc[8] = {};
    for (int w0 = 0; w0 < deg; w0 += 32) {
        int mye = w0 + l32;
        int c = (mye < deg) ? col[e0 + mye] : 0;
        int nch = min(deg - w0, 32);
        for (int base = 0; base < nch; base += 16) {
            uint2 v[8];
            float wj[8];
#pragma unroll
            for (int u = 0; u < 8; ++u) {
                int j = base + u * 2 + sub;
                int cj = __shfl(c, (half << 5) | (j & 31));
                bool ok = (j < nch);
                wj[u] = ok ? 1.f : 0.f;
                int cs = ok ? cj : 0;
                v[u] = *(const uint2*)(h8 + (size_t)cs * ROWB + foff);
            }
#pragma unroll
            for (int u = 0; u < 8; ++u) {
                floatx2 f0 = __builtin_amdgcn_cvt_pk_f32_fp8(v[u].x, false);
                floatx2 f1 = __builtin_amdgcn_cvt_pk_f32_fp8(v[u].x, true);
                floatx2 f2 = __builtin_amdgcn_cvt_pk_f32_fp8(v[u].y, false);
                floatx2 f3 = __builtin_amdgcn_cvt_pk_f32_fp8(v[u].y, true);
                acc[0] += wj[u] * f0.x;
                acc[1] += wj[u] * f0.y;
                acc[2] += wj[u] * f1.x;
                acc[3] += wj[u] * f1.y;
                acc[4] += wj[u] * f2.x;
                acc[5] += wj[u] * f2.y;
                acc[6] += wj[u] * f3.x;
                acc[7] += wj[u] * f3.y;
            }
        }
    }
#pragma unroll
    for (int i = 0; i < 8; ++i) acc[i] += __shfl_xor(acc[i], 16);

    // epilogue on all lanes (clamped addresses) so cross-k shuffles are safe
    size_t oc = ((size_t)kk * N + (valid ? node : 0)) * F + fqc * 8;
    uint4 rv = *(const uint4*)(rootb + oc);
    const float* bp = bias + kk * F + fqc * 8;
    float4 b0 = *(const float4*)(bp);
    float4 b1 = *(const float4*)(bp + 4);
    const unsigned int ru[4] = {rv.x, rv.y, rv.z, rv.w};
    float res[8];
#pragma unroll
    for (int q = 0; q < 4; ++q) {
        float rlo = __uint_as_float(ru[q] << 16);
        float rhi = __uint_as_float(ru[q] & 0xffff0000u);
        float blo = (q < 2) ? ((q == 0) ? b0.x : b0.z) : ((q == 2) ? b1.x : b1.z);
        float bhi = (q < 2) ? ((q == 0) ? b0.y : b0.w) : ((q == 2) ? b1.y : b1.w);
        res[2 * q] = acc[2 * q] * dv + rlo + blo;
        res[2 * q + 1] = acc[2 * q + 1] * dv + rhi + bhi;
    }
    if (do_relu) {
#pragma unroll
        for (int i = 0; i < 8; ++i) res[i] = fmaxf(res[i], 0.f);
    }
    if (mode == 0) {
        if (sub == 0 && fqq < FH && valid) {
            size_t o = ((size_t)kk * N + node) * F + fqq * 8;
            uint4 w;
            w.x = pack_bf16x2(res[0], res[1]);
            w.y = pack_bf16x2(res[2], res[3]);
            w.z = pack_bf16x2(res[4], res[5]);
            w.w = pack_bf16x2(res[6], res[7]);
            *(uint4*)((unsigned short*)out + o) = w;
        }
    } else {
        // mean over k: partner lane is fq^8 (same sub, other k)
        float mres[8];
#pragma unroll
        for (int i = 0; i < 8; ++i) mres[i] = 0.5f * (res[i] + __shfl_xor(res[i], 8));
        if (mode == 1) {
            if (sub == 0 && kk == 0 && fqq < FH && valid) {
                size_t o = (size_t)node * F + fqq * 8;
                *(float4*)((float*)out + o) = make_float4(mres[0], mres[1], mres[2], mres[3]);
                *(float4*)((float*)out + o + 4) = make_float4(mres[4], mres[5], mres[6], mres[7]);
            }
        } else {
            // mode 2: in-wave log_softmax over the F valid feats (octets fqq<FH)
            bool act = (fqq < FH);
            float lm = -INFINITY;
            if (act) {
#pragma unroll
                for (int i = 0; i < 8; ++i) lm = fmaxf(lm, mres[i]);
            }
#pragma unroll
            for (int m = 1; m < 8; m <<= 1) lm = fmaxf(lm, __shfl_xor(lm, m));
            float ls = 0.f;
            if (act) {
#pragma unroll
                for (int i = 0; i < 8; ++i) ls += expf(mres[i] - lm);
            }
#pragma unroll
            for (int m = 1; m < 8; m <<= 1) ls += __shfl_xor(ls, m);
            float lg = lm + logf(ls);
            if (sub == 0 && kk == 0 && act && valid) {
                size_t o = (size_t)node * F + fqq * 8;
                *(float4*)((float*)out + o) =
                    make_float4(mres[0] - lg, mres[1] - lg, mres[2] - lg, mres[3] - lg);
                *(float4*)((float*)out + o + 4) =
                    make_float4(mres[4] - lg, mres[5] - lg, mres[6] - lg, mres[7] - lg);
            }
        }
    }
}

// ---------------- launch ----------------

static inline size_t align256(size_t x) { return (x + 255) & ~(size_t)255; }

extern "C" void kernel_launch(void* const* d_in, const int* in_sizes, int n_in,
                              void* d_out, int out_size, void* d_ws, size_t ws_size,
                              hipStream_t stream) {
    const float* x = (const float*)d_in[0];
    const int* ei = (const int*)d_in[1];
    const float* w1_init = (const float*)d_in[2];
    const float* w1 = (const float*)d_in[3];
    const float* v1 = (const float*)d_in[4];
    const float* b1 = (const float*)d_in[5];
    const float* w2_init = (const float*)d_in[6];
    const float* w2 = (const float*)d_in[7];
    const float* v2 = (const float*)d_in[8];
    const float* b2 = (const float*)d_in[9];

    const int N = in_sizes[0] / F_IN;
    const int E = in_sizes[1] / 2;
    const int* src = ei;
    const int* dst = ei + E;

    char* p = (char*)d_ws;
    auto take = [&](size_t bytes) {
        char* r = p;
        p += align256(bytes);
        return r;
    };
    float* dinv = (float*)take((size_t)N * 4);
    int* row_ptr = (int*)take((size_t)(N + 1) * 4);
    int* tileSums = (int*)take(256 * 4);
    int* counts = (int*)take((size_t)256 * NBLK_CNT * 4);
    int* scanned = (int*)take((size_t)256 * NBLK_CNT * 4);
    unsigned int* pairs = (unsigned int*)take((size_t)E * 4);
    int* col = (int*)take((size_t)E * 4);
    unsigned short* v1t = (unsigned short*)take((size_t)2 * 64 * 128 * 2);
    unsigned short* w1it = (unsigned short*)take((size_t)2 * 64 * 128 * 2);
    unsigned short* w1t = (unsigned short*)take((size_t)2 * 64 * 64 * 2);
    unsigned short* v2t = (unsigned short*)take((size_t)2 * 40 * 64 * 2);
    unsigned short* w2it = (unsigned short*)take((size_t)2 * 40 * 64 * 2);
    unsigned short* w2t = (unsigned short*)take((size_t)2 * 40 * 64 * 2);
    unsigned short* rootb = (unsigned short*)take((size_t)K_STACKS * N * HID * 2);
    unsigned char* hb8 = (unsigned char*)take((size_t)K_STACKS * N * HID);  // fp8 gather table
    unsigned short* hc = (unsigned short*)take((size_t)K_STACKS * N * HID * 2);
    float* h1 = (float*)take((size_t)N * HID * 4);

    const int TB = 256;
    const int nCnt = 256 * NBLK_CNT;           // 65536
    const int nScanBlocks = nCnt / SCAN_TILE;  // 64
    const int nBuckets = (N + 255) / 256;      // 196
    const int ntiles = (N + 63) / 64;          // 782

    hipMemsetAsync(tileSums, 0, 256, stream);
    count_kernel<<<NBLK_CNT, 256, 0, stream>>>(dst, counts, tileSums, E);
    scan_phase3_excl<<<nScanBlocks, 256, 0, stream>>>(counts, tileSums, scanned, nCnt);
    bucket_scatter_kernel<<<NBLK_CNT, 256, 0, stream>>>(src, dst, scanned, pairs, E);
    csr_build_kernel<<<nBuckets, 256, 0, stream>>>(pairs, scanned, row_ptr, dinv, col, N, E);

    wt_all_kernel<<<(56320 + TB - 1) / TB, TB, 0, stream>>>(v1, w1_init, w1, v2, w2_init, w2,
                                                            v1t, w1it, w1t, v2t, w2it, w2t);

    dim3 ggrid(ntiles, K_STACKS);
    const int agg_blocks = ((N + 1) / 2 + 3) / 4;  // 2 nodes per wave, 4 waves per block

    // ----- layer 1: F_IN=128 -> HID=64, act=relu -----
    gemm2_mfma<128><<<ntiles, 256, 0, stream>>>(x, v1t, w1it, rootb, hb8, dinv, N, HID, 128, 0);
    agg_kernel<HID><<<agg_blocks, 256, 0, stream>>>(hb8, row_ptr, col, dinv, rootb, b1, hc, N, 1, 0);
    gemm_mfma<64><<<ggrid, 256, 0, stream>>>(hc, w1t, hb8, dinv, N, HID, 64, 1, 1, 1, 1, 1);
    agg_kernel<HID><<<agg_blocks, 256, 0, stream>>>(hb8, row_ptr, col, dinv, rootb, b1, h1, N, 1, 1);

    // ----- layer 2: HID=64 -> NCLS=40, act=identity; final agg fuses mean+log_softmax -----
    gemm2_mfma<64><<<ntiles, 256, 0, stream>>>(h1, v2t, w2it, rootb, hb8, dinv, N, NCLS, 64, 0);
    agg_kernel<NCLS><<<agg_blocks, 256, 0, stream>>>(hb8, row_ptr, col, dinv, rootb, b2, hc, N, 0, 0);
    gemm_mfma<64><<<ggrid, 256, 0, stream>>>(hc, w2t, hb8, dinv, N, NCLS, 40, 1, 1, 1, 1, 1);
    agg_kernel<NCLS><<<agg_blocks, 256, 0, stream>>>(hb8, row_ptr, col, dinv, rootb, b2,
                                                     (float*)d_out, N, 0, 2);
}

// Round 13
// 281.652 us; speedup vs baseline: 1.0227x; 1.0227x over previous
//
#include <hip/hip_runtime.h>
#include <hip/hip_bf16.h>
#include <math.h>

#define N_NODES 50000
#define F_IN 128
#define HID 64
#define NCLS 40
#define K_STACKS 2
#define SCAN_TILE 1024
#define NBLK_CNT 256  // radix blocks; 256 buckets of 256 node-ids (N=50000 -> 196 used)

typedef __attribute__((ext_vector_type(8))) short short8;
typedef __attribute__((ext_vector_type(4))) float floatx4;
typedef __attribute__((ext_vector_type(2))) float floatx2;

__device__ __forceinline__ unsigned int f32_to_bf16_bits(float f) {
    unsigned int u = __float_as_uint(f);
    return (u + 0x7fffu + ((u >> 16) & 1u)) >> 16;  // RNE
}
__device__ __forceinline__ unsigned int pack_bf16x2(float a, float b) {
    return f32_to_bf16_bits(a) | (f32_to_bf16_bits(b) << 16);
}
__device__ __forceinline__ unsigned char f32_to_fp8(float v) {
    int pk = __builtin_amdgcn_cvt_pk_fp8_f32(v, v, 0, false);  // OCP e4m3 on gfx950
    return (unsigned char)(pk & 0xff);
}

// ---------------- CSR build via radix bucketing (dst>>8) ----------------
// NOTE: packing src into 16 bits requires N <= 65536 (here N=50000).

// counts histogram + per-scan-tile sums (tile i covers buckets 4i..4i+3)
__global__ __launch_bounds__(256) void count_kernel(const int* __restrict__ dst,
                                                    int* __restrict__ counts,
                                                    int* __restrict__ tileSums, int E) {
    __shared__ int hist[256];
    __shared__ int ts[64];
    int blk = blockIdx.x, t = threadIdx.x;
    hist[t] = 0;
    if (t < 64) ts[t] = 0;
    __syncthreads();
    int chunk = (E + NBLK_CNT - 1) / NBLK_CNT;
    int s = blk * chunk, e = min(E, s + chunk);
    for (int i = s + t; i < e; i += 256) atomicAdd(&hist[dst[i] >> 8], 1);
    __syncthreads();
    counts[t * NBLK_CNT + blk] = hist[t];  // bucket-major
    atomicAdd(&ts[t >> 2], hist[t]);
    __syncthreads();
    if (t < 64) atomicAdd(&tileSums[t], ts[t]);
}

// exclusive scan of counts; tile offsets computed in-block from tileSums
__global__ __launch_bounds__(256) void scan_phase3_excl(const int* __restrict__ in,
                                                        const int* __restrict__ tileSums,
                                                        int* __restrict__ out, int n) {
    __shared__ int lds[256];
    __shared__ int tsum[64];
    int b = blockIdx.x, t = threadIdx.x;
    if (t < 64) tsum[t] = tileSums[t];
    int base = b * SCAN_TILE + t * 4;
    int e[4];
    int s = 0;
#pragma unroll
    for (int i = 0; i < 4; ++i) {
        e[i] = (base + i < n) ? in[base + i] : 0;
        s += e[i];
    }
    lds[t] = s;
    __syncthreads();
    int v = s;
    for (int off = 1; off < 256; off <<= 1) {
        int add = (t >= off) ? lds[t - off] : 0;
        __syncthreads();
        v += add;
        lds[t] = v;
        __syncthreads();
    }
    int toff = 0;
    for (int i = 0; i < b; ++i) toff += tsum[i];
    int run = (t == 0 ? 0 : lds[t - 1]) + toff;
#pragma unroll
    for (int i = 0; i < 4; ++i) {
        if (base + i < n) {
            out[base + i] = run;
            run += e[i];
        }
    }
}

// dense bucketed writes: each block owns pre-reserved runs per bucket
__global__ __launch_bounds__(256) void bucket_scatter_kernel(const int* __restrict__ src,
                                                             const int* __restrict__ dst,
                                                             const int* __restrict__ scanned,
                                                             unsigned int* __restrict__ pairs,
                                                             int E) {
    __shared__ int cur[256];
    int blk = blockIdx.x, t = threadIdx.x;
    cur[t] = scanned[t * NBLK_CNT + blk];
    __syncthreads();
    int chunk = (E + NBLK_CNT - 1) / NBLK_CNT;
    int s0 = blk * chunk, e0 = min(E, s0 + chunk);
    for (int i = s0 + t; i < e0; i += 256) {
        int d = dst[i];
        int pos = atomicAdd(&cur[d >> 8], 1);
        pairs[pos] = (unsigned int)src[i] | ((unsigned int)(d & 255) << 16);
    }
}

// one block per bucket: local deg hist -> scan -> row_ptr/dinv/col (all L2-local)
__global__ __launch_bounds__(256) void csr_build_kernel(const unsigned int* __restrict__ pairs,
                                                        const int* __restrict__ scanned,
                                                        int* __restrict__ row_ptr,
                                                        float* __restrict__ dinv,
                                                        int* __restrict__ col, int N, int E) {
    __shared__ int degl[256], lds[256], curl[256], sb[2];
    int b = blockIdx.x, t = threadIdx.x;
    if (t == 0) {
        sb[0] = scanned[b * NBLK_CNT];
        sb[1] = (b + 1 < 256) ? scanned[(b + 1) * NBLK_CNT] : E;
    }
    degl[t] = 0;
    __syncthreads();
    int bstart = sb[0], bend = sb[1];
    for (int e = bstart + t; e < bend; e += 256) {
        atomicAdd(&degl[(pairs[e] >> 16) & 255], 1);
    }
    __syncthreads();
    int d = degl[t];
    lds[t] = d;
    __syncthreads();
    int v = d;
    for (int off = 1; off < 256; off <<= 1) {
        int add = (t >= off) ? lds[t - off] : 0;
        __syncthreads();
        v += add;
        lds[t] = v;
        __syncthreads();
    }
    int excl = v - d;
    int node = b * 256 + t;
    if (node <= N) row_ptr[node] = bstart + excl;
    if (node < N) dinv[node] = (d > 0) ? (1.0f / sqrtf((float)d)) : 0.0f;
    curl[t] = excl;
    __syncthreads();
    for (int e = bstart + t; e < bend; e += 256) {
        unsigned int p = pairs[e];
        int ln = (p >> 16) & 255;
        int pos = atomicAdd(&curl[ln], 1);
        col[bstart + pos] = (int)(p & 0xffffu);
    }
}

// ---------------- fused weight pre-transpose: [k][C][F] fp32 -> [k][F][CP] bf16 ----------
__device__ __forceinline__ void wt_one(const float* __restrict__ in,
                                       unsigned short* __restrict__ out, int li, int C, int F,
                                       int CP) {
    int k = li / (F * CP);
    int r = li - k * F * CP;
    int f = r / CP;
    int c = r - f * CP;
    out[li] = (c < C) ? (unsigned short)f32_to_bf16_bits(in[((size_t)k * C + c) * F + f]) : 0;
}

__global__ void wt_all_kernel(const float* v1, const float* w1i, const float* w1,
                              const float* v2, const float* w2i, const float* w2,
                              unsigned short* v1t, unsigned short* w1it, unsigned short* w1t,
                              unsigned short* v2t, unsigned short* w2it, unsigned short* w2t) {
    int i = blockIdx.x * blockDim.x + threadIdx.x;
    if (i < 16384) wt_one(v1, v1t, i, 128, 64, 128);
    else if (i < 32768) wt_one(w1i, w1it, i - 16384, 128, 64, 128);
    else if (i < 40960) wt_one(w1, w1t, i - 32768, 64, 64, 64);
    else if (i < 46080) wt_one(v2, v2t, i - 40960, 64, 40, 64);
    else if (i < 51200) wt_one(w2i, w2it, i - 46080, 64, 40, 64);
    else if (i < 56320) wt_one(w2, w2t, i - 51200, 40, 40, 64);
}

// ---------------- staging helpers ----------------
template <int CINP>
__device__ __forceinline__ void stage_A(const void* A, unsigned short* At, size_t abase,
                                        int n0, int t, int N, int CREAL, int a_bf16) {
    constexpr int CP8 = CINP / 8;
    constexpr int MS = CP8 - 1;
    constexpr int SH = (CP8 == 16) ? 4 : 3;
    for (int i = t; i < 64 * CP8; i += 256) {
        int n = i >> SH;
        int c = i & MS;
        uint4 w = make_uint4(0u, 0u, 0u, 0u);
        int gn = n0 + n;
        if (gn < N && c * 8 < CREAL) {
            if (a_bf16) {
                w = *(const uint4*)((const unsigned short*)A + abase + (size_t)gn * CREAL + c * 8);
            } else {
                const float* srcp = (const float*)A + abase + (size_t)gn * CREAL + c * 8;
                float4 f0 = *(const float4*)(srcp);
                float4 f1 = *(const float4*)(srcp + 4);
                w.x = pack_bf16x2(f0.x, f0.y);
                w.y = pack_bf16x2(f0.z, f0.w);
                w.z = pack_bf16x2(f1.x, f1.y);
                w.w = pack_bf16x2(f1.z, f1.w);
            }
        }
        *(uint4*)(At + n * CINP + ((c ^ (n & MS)) << 3)) = w;
    }
}

template <int CINP>
__device__ __forceinline__ void stage_B(const unsigned short* Bk, unsigned short* Bs, int t,
                                        int COUT) {
    constexpr int CP8 = CINP / 8;
    constexpr int MS = CP8 - 1;
    constexpr int SH = (CP8 == 16) ? 4 : 3;
    for (int i = t; i < COUT * CP8; i += 256) {
        int f = i >> SH;
        int c = i & MS;
        uint4 w = *(const uint4*)(Bk + f * CINP + c * 8);
        *(uint4*)(Bs + f * CINP + ((c ^ (f & MS)) << 3)) = w;
    }
}

// ---------------- MFMA GEMM (single output, per-k grid) ----------------
// out_inter=1 + out_fp8=1: fp8 gather-table [node][k][COUT]; else f32 std.
template <int CINP>
__global__ __launch_bounds__(256) void gemm_mfma(
    const void* __restrict__ A, const unsigned short* __restrict__ Bt,
    void* __restrict__ out, const float* __restrict__ scale, int N, int COUT, int CREAL,
    int a_per_k, int a_bf16, int out_fp8, int do_scale, int out_inter) {
    constexpr int MS = CINP / 8 - 1;
    __shared__ __align__(16) unsigned short At[64 * CINP];
    __shared__ __align__(16) unsigned short Bs[64 * CINP];

    const int k = blockIdx.y;
    const int n0 = blockIdx.x * 64;
    const int t = threadIdx.x;
    stage_A<CINP>(A, At, a_per_k ? (size_t)k * N * CREAL : (size_t)0, n0, t, N, CREAL, a_bf16);
    stage_B<CINP>(Bt + (size_t)k * COUT * CINP, Bs, t, COUT);
    __syncthreads();

    const int lane = t & 63;
    const int wv = t >> 6;
    const int quad = lane >> 4;
    const int li = lane & 15;
    const int m0 = wv * 16;

    floatx4 acc[4] = {{0.f, 0.f, 0.f, 0.f}, {0.f, 0.f, 0.f, 0.f},
                      {0.f, 0.f, 0.f, 0.f}, {0.f, 0.f, 0.f, 0.f}};
    const int am = (m0 + li) & MS;
#pragma unroll
    for (int kc = 0; kc < CINP / 32; ++kc) {
        int cc = kc * 4 + quad;
        short8 a = *(const short8*)(At + (m0 + li) * CINP + ((cc ^ am) << 3));
#pragma unroll
        for (int nt = 0; nt < 4; ++nt) {
            if (nt * 16 < COUT) {
                int f = nt * 16 + li;
                short8 b = *(const short8*)(Bs + f * CINP + ((cc ^ (f & MS)) << 3));
                acc[nt] = __builtin_amdgcn_mfma_f32_16x16x32_bf16(a, b, acc[nt], 0, 0, 0);
            }
        }
    }

    float sc[4] = {1.f, 1.f, 1.f, 1.f};
    if (do_scale) {
#pragma unroll
        for (int r = 0; r < 4; ++r) {
            int node = n0 + m0 + quad * 4 + r;
            sc[r] = (node < N) ? scale[node] : 1.f;
        }
    }
#pragma unroll
    for (int nt = 0; nt < 4; ++nt) {
        if (nt * 16 >= COUT) continue;
        int f = nt * 16 + li;
        if (f >= COUT) continue;
#pragma unroll
        for (int r = 0; r < 4; ++r) {
            int node = n0 + m0 + quad * 4 + r;
            if (node < N) {
                float val = acc[nt][r] * sc[r];
                if (out_inter) {
                    size_t o = (size_t)node * 2 * COUT + (size_t)k * COUT + f;
                    if (out_fp8)
                        ((unsigned char*)out)[o] = f32_to_fp8(val);
                    else
                        ((unsigned short*)out)[o] = (unsigned short)f32_to_bf16_bits(val);
                } else {
                    size_t o = ((size_t)k * N + node) * COUT + f;
                    ((float*)out)[o] = val;
                }
            }
        }
    }
}

// ---------------- MFMA GEMM fused pair (per-k grid, round-11 form) ----------------
// shared A -> root (bf16 std [k][N][COUT]) + table (fp8 inter [node][k][COUT], dinv-scaled)
template <int CINP>
__global__ __launch_bounds__(256) void gemm2_mfma(
    const void* __restrict__ A, const unsigned short* __restrict__ Bt1,
    const unsigned short* __restrict__ Bt2, unsigned short* __restrict__ out1,
    unsigned char* __restrict__ out2, const float* __restrict__ scale, int N, int COUT,
    int CREAL, int a_bf16) {
    constexpr int MS = CINP / 8 - 1;
    __shared__ __align__(16) unsigned short At[64 * CINP];
    __shared__ __align__(16) unsigned short Bs1[64 * CINP];
    __shared__ __align__(16) unsigned short Bs2[64 * CINP];

    const int k = blockIdx.y;
    const int n0 = blockIdx.x * 64;
    const int t = threadIdx.x;
    stage_A<CINP>(A, At, (size_t)0, n0, t, N, CREAL, a_bf16);
    stage_B<CINP>(Bt1 + (size_t)k * COUT * CINP, Bs1, t, COUT);
    stage_B<CINP>(Bt2 + (size_t)k * COUT * CINP, Bs2, t, COUT);
    __syncthreads();

    const int lane = t & 63;
    const int wv = t >> 6;
    const int quad = lane >> 4;
    const int li = lane & 15;
    const int m0 = wv * 16;

    floatx4 acc1[4] = {{0.f, 0.f, 0.f, 0.f}, {0.f, 0.f, 0.f, 0.f},
                       {0.f, 0.f, 0.f, 0.f}, {0.f, 0.f, 0.f, 0.f}};
    floatx4 acc2[4] = {{0.f, 0.f, 0.f, 0.f}, {0.f, 0.f, 0.f, 0.f},
                       {0.f, 0.f, 0.f, 0.f}, {0.f, 0.f, 0.f, 0.f}};
    const int am = (m0 + li) & MS;
#pragma unroll
    for (int kc = 0; kc < CINP / 32; ++kc) {
        int cc = kc * 4 + quad;
        short8 a = *(const short8*)(At + (m0 + li) * CINP + ((cc ^ am) << 3));
#pragma unroll
        for (int nt = 0; nt < 4; ++nt) {
            if (nt * 16 < COUT) {
                int f = nt * 16 + li;
                int bo = f * CINP + ((cc ^ (f & MS)) << 3);
                short8 b1 = *(const short8*)(Bs1 + bo);
                short8 b2 = *(const short8*)(Bs2 + bo);
                acc1[nt] = __builtin_amdgcn_mfma_f32_16x16x32_bf16(a, b1, acc1[nt], 0, 0, 0);
                acc2[nt] = __builtin_amdgcn_mfma_f32_16x16x32_bf16(a, b2, acc2[nt], 0, 0, 0);
            }
        }
    }

    float sc[4];
#pragma unroll
    for (int r = 0; r < 4; ++r) {
        int node = n0 + m0 + quad * 4 + r;
        sc[r] = (node < N) ? scale[node] : 1.f;
    }
#pragma unroll
    for (int nt = 0; nt < 4; ++nt) {
        if (nt * 16 >= COUT) continue;
        int f = nt * 16 + li;
        if (f >= COUT) continue;
#pragma unroll
        for (int r = 0; r < 4; ++r) {
            int node = n0 + m0 + quad * 4 + r;
            if (node < N) {
                out1[((size_t)k * N + node) * COUT + f] =
                    (unsigned short)f32_to_bf16_bits(acc1[nt][r]);
                out2[(size_t)node * 2 * COUT + (size_t)k * COUT + f] =
                    f32_to_fp8(acc2[nt][r] * sc[r]);
            }
        }
    }
}

// ---------------- Sparse aggregation v8: fp8 table, 2 nodes/wave, fused mean+lsm --------
// h8 interleaved [node][k][F] fp8 (pre-scaled by dinv[src]). Each 32-lane half owns a node.
// mode 0: bf16 std [k][N][F] out.  mode 1: fp32 mean-over-k out [N][F].
// mode 2: mean-over-k -> in-wave log_softmax over F=NCLS feats -> fp32 out [N][F].
template <int F>
__global__ __launch_bounds__(256) void agg_kernel(
    const unsigned char* __restrict__ h8, const int* __restrict__ row_ptr,
    const int* __restrict__ col, const float* __restrict__ dinv,
    const unsigned short* __restrict__ rootb, const float* __restrict__ bias,
    void* __restrict__ out, int N, int do_relu, int mode) {
    constexpr int FH = F / 8;
    constexpr int ROWB = 2 * F;  // interleaved row bytes (fp8)
    int wid = (blockIdx.x * blockDim.x + threadIdx.x) >> 6;
    int lane = threadIdx.x & 63;
    int half = lane >> 5;
    int l32 = lane & 31;
    int node = wid * 2 + half;
    bool valid = node < N;
    int e0 = 0, deg = 0;
    float dv = 0.f;
    if (valid) {
        e0 = row_ptr[node];
        deg = row_ptr[node + 1] - e0;
        dv = dinv[node];
    }
    const int sub = l32 >> 4;
    const int fq = l32 & 15;
    const int kk = fq >> 3;
    const int fqq = fq & 7;
    const int fqc = (fqq < FH) ? fqq : (FH - 1);
    const int foff = kk * F + fqc * 8;

    float acc[8] = {};
    for (int w0 = 0; w0 < deg; w0 += 32) {
        int mye = w0 + l32;
        int c = (mye < deg) ? col[e0 + mye] : 0;
        int nch = min(deg - w0, 32);
        for (int base = 0; base < nch; base += 16) {
            uint2 v[8];
            float wj[8];
#pragma unroll
            for (int u = 0; u < 8; ++u) {
                int j = base + u * 2 + sub;
                int cj = __shfl(c, (half << 5) | (j & 31));
                bool ok = (j < nch);
                wj[u] = ok ? 1.f : 0.f;
                int cs = ok ? cj : 0;
                v[u] = *(const uint2*)(h8 + (size_t)cs * ROWB + foff);
            }
#pragma unroll
            for (int u = 0; u < 8; ++u) {
                floatx2 f0 = __builtin_amdgcn_cvt_pk_f32_fp8(v[u].x, false);
                floatx2 f1 = __builtin_amdgcn_cvt_pk_f32_fp8(v[u].x, true);
                floatx2 f2 = __builtin_amdgcn_cvt_pk_f32_fp8(v[u].y, false);
                floatx2 f3 = __builtin_amdgcn_cvt_pk_f32_fp8(v[u].y, true);
                acc[0] += wj[u] * f0.x;
                acc[1] += wj[u] * f0.y;
                acc[2] += wj[u] * f1.x;
                acc[3] += wj[u] * f1.y;
                acc[4] += wj[u] * f2.x;
                acc[5] += wj[u] * f2.y;
                acc[6] += wj[u] * f3.x;
                acc[7] += wj[u] * f3.y;
            }
        }
    }
#pragma unroll
    for (int i = 0; i < 8; ++i) acc[i] += __shfl_xor(acc[i], 16);

    // epilogue on all lanes (clamped addresses) so cross-k shuffles are safe
    size_t oc = ((size_t)kk * N + (valid ? node : 0)) * F + fqc * 8;
    uint4 rv = *(const uint4*)(rootb + oc);
    const float* bp = bias + kk * F + fqc * 8;
    float4 b0 = *(const float4*)(bp);
    float4 b1 = *(const float4*)(bp + 4);
    const unsigned int ru[4] = {rv.x, rv.y, rv.z, rv.w};
    float res[8];
#pragma unroll
    for (int q = 0; q < 4; ++q) {
        float rlo = __uint_as_float(ru[q] << 16);
        float rhi = __uint_as_float(ru[q] & 0xffff0000u);
        float blo = (q < 2) ? ((q == 0) ? b0.x : b0.z) : ((q == 2) ? b1.x : b1.z);
        float bhi = (q < 2) ? ((q == 0) ? b0.y : b0.w) : ((q == 2) ? b1.y : b1.w);
        res[2 * q] = acc[2 * q] * dv + rlo + blo;
        res[2 * q + 1] = acc[2 * q + 1] * dv + rhi + bhi;
    }
    if (do_relu) {
#pragma unroll
        for (int i = 0; i < 8; ++i) res[i] = fmaxf(res[i], 0.f);
    }
    if (mode == 0) {
        if (sub == 0 && fqq < FH && valid) {
            size_t o = ((size_t)kk * N + node) * F + fqq * 8;
            uint4 w;
            w.x = pack_bf16x2(res[0], res[1]);
            w.y = pack_bf16x2(res[2], res[3]);
            w.z = pack_bf16x2(res[4], res[5]);
            w.w = pack_bf16x2(res[6], res[7]);
            *(uint4*)((unsigned short*)out + o) = w;
        }
    } else {
        // mean over k: partner lane is fq^8 (same sub, other k)
        float mres[8];
#pragma unroll
        for (int i = 0; i < 8; ++i) mres[i] = 0.5f * (res[i] + __shfl_xor(res[i], 8));
        if (mode == 1) {
            if (sub == 0 && kk == 0 && fqq < FH && valid) {
                size_t o = (size_t)node * F + fqq * 8;
                *(float4*)((float*)out + o) = make_float4(mres[0], mres[1], mres[2], mres[3]);
                *(float4*)((float*)out + o + 4) = make_float4(mres[4], mres[5], mres[6], mres[7]);
            }
        } else {
            // mode 2: in-wave log_softmax over the F valid feats (octets fqq<FH)
            bool act = (fqq < FH);
            float lm = -INFINITY;
            if (act) {
#pragma unroll
                for (int i = 0; i < 8; ++i) lm = fmaxf(lm, mres[i]);
            }
#pragma unroll
            for (int m = 1; m < 8; m <<= 1) lm = fmaxf(lm, __shfl_xor(lm, m));
            float ls = 0.f;
            if (act) {
#pragma unroll
                for (int i = 0; i < 8; ++i) ls += expf(mres[i] - lm);
            }
#pragma unroll
            for (int m = 1; m < 8; m <<= 1) ls += __shfl_xor(ls, m);
            float lg = lm + logf(ls);
            if (sub == 0 && kk == 0 && act && valid) {
                size_t o = (size_t)node * F + fqq * 8;
                *(float4*)((float*)out + o) =
                    make_float4(mres[0] - lg, mres[1] - lg, mres[2] - lg, mres[3] - lg);
                *(float4*)((float*)out + o + 4) =
                    make_float4(mres[4] - lg, mres[5] - lg, mres[6] - lg, mres[7] - lg);
            }
        }
    }
}

// ---------------- launch ----------------

static inline size_t align256(size_t x) { return (x + 255) & ~(size_t)255; }

extern "C" void kernel_launch(void* const* d_in, const int* in_sizes, int n_in,
                              void* d_out, int out_size, void* d_ws, size_t ws_size,
                              hipStream_t stream) {
    const float* x = (const float*)d_in[0];
    const int* ei = (const int*)d_in[1];
    const float* w1_init = (const float*)d_in[2];
    const float* w1 = (const float*)d_in[3];
    const float* v1 = (const float*)d_in[4];
    const float* b1 = (const float*)d_in[5];
    const float* w2_init = (const float*)d_in[6];
    const float* w2 = (const float*)d_in[7];
    const float* v2 = (const float*)d_in[8];
    const float* b2 = (const float*)d_in[9];

    const int N = in_sizes[0] / F_IN;
    const int E = in_sizes[1] / 2;
    const int* src = ei;
    const int* dst = ei + E;

    char* p = (char*)d_ws;
    auto take = [&](size_t bytes) {
        char* r = p;
        p += align256(bytes);
        return r;
    };
    float* dinv = (float*)take((size_t)N * 4);
    int* row_ptr = (int*)take((size_t)(N + 1) * 4);
    int* tileSums = (int*)take(256 * 4);
    int* counts = (int*)take((size_t)256 * NBLK_CNT * 4);
    int* scanned = (int*)take((size_t)256 * NBLK_CNT * 4);
    unsigned int* pairs = (unsigned int*)take((size_t)E * 4);
    int* col = (int*)take((size_t)E * 4);
    unsigned short* v1t = (unsigned short*)take((size_t)2 * 64 * 128 * 2);
    unsigned short* w1it = (unsigned short*)take((size_t)2 * 64 * 128 * 2);
    unsigned short* w1t = (unsigned short*)take((size_t)2 * 64 * 64 * 2);
    unsigned short* v2t = (unsigned short*)take((size_t)2 * 40 * 64 * 2);
    unsigned short* w2it = (unsigned short*)take((size_t)2 * 40 * 64 * 2);
    unsigned short* w2t = (unsigned short*)take((size_t)2 * 40 * 64 * 2);
    unsigned short* rootb = (unsigned short*)take((size_t)K_STACKS * N * HID * 2);
    unsigned char* hb8 = (unsigned char*)take((size_t)K_STACKS * N * HID);  // fp8 gather table
    unsigned short* hc = (unsigned short*)take((size_t)K_STACKS * N * HID * 2);
    float* h1 = (float*)take((size_t)N * HID * 4);

    const int TB = 256;
    const int nCnt = 256 * NBLK_CNT;           // 65536
    const int nScanBlocks = nCnt / SCAN_TILE;  // 64
    const int nBuckets = (N + 255) / 256;      // 196
    const int ntiles = (N + 63) / 64;          // 782

    hipMemsetAsync(tileSums, 0, 256, stream);
    count_kernel<<<NBLK_CNT, 256, 0, stream>>>(dst, counts, tileSums, E);
    scan_phase3_excl<<<nScanBlocks, 256, 0, stream>>>(counts, tileSums, scanned, nCnt);
    bucket_scatter_kernel<<<NBLK_CNT, 256, 0, stream>>>(src, dst, scanned, pairs, E);
    csr_build_kernel<<<nBuckets, 256, 0, stream>>>(pairs, scanned, row_ptr, dinv, col, N, E);

    wt_all_kernel<<<(56320 + TB - 1) / TB, TB, 0, stream>>>(v1, w1_init, w1, v2, w2_init, w2,
                                                            v1t, w1it, w1t, v2t, w2it, w2t);

    dim3 ggrid(ntiles, K_STACKS);
    const int agg_blocks = ((N + 1) / 2 + 3) / 4;  // 2 nodes per wave, 4 waves per block

    // ----- layer 1: F_IN=128 -> HID=64, act=relu -----
    gemm2_mfma<128><<<ggrid, 256, 0, stream>>>(x, v1t, w1it, rootb, hb8, dinv, N, HID, 128, 0);
    agg_kernel<HID><<<agg_blocks, 256, 0, stream>>>(hb8, row_ptr, col, dinv, rootb, b1, hc, N, 1, 0);
    gemm_mfma<64><<<ggrid, 256, 0, stream>>>(hc, w1t, hb8, dinv, N, HID, 64, 1, 1, 1, 1, 1);
    agg_kernel<HID><<<agg_blocks, 256, 0, stream>>>(hb8, row_ptr, col, dinv, rootb, b1, h1, N, 1, 1);

    // ----- layer 2: HID=64 -> NCLS=40, act=identity; final agg fuses mean+log_softmax -----
    gemm2_mfma<64><<<ggrid, 256, 0, stream>>>(h1, v2t, w2it, rootb, hb8, dinv, N, NCLS, 64, 0);
    agg_kernel<NCLS><<<agg_blocks, 256, 0, stream>>>(hb8, row_ptr, col, dinv, rootb, b2, hc, N, 0, 0);
    gemm_mfma<64><<<ggrid, 256, 0, stream>>>(hc, w2t, hb8, dinv, N, NCLS, 40, 1, 1, 1, 1, 1);
    agg_kernel<NCLS><<<agg_blocks, 256, 0, stream>>>(hb8, row_ptr, col, dinv, rootb, b2,
                                                     (float*)d_out, N, 0, 2);
}